// Round 7
// baseline (444.718 us; speedup 1.0000x reference)
//
#include <hip/hip_runtime.h>

#define N 8192
#define DIN 512
#define DOUT 256
#define ALPHA 0.2f
#define NEG_INF -9.0e15f

typedef __attribute__((ext_vector_type(8))) short bf16x8;
typedef __attribute__((ext_vector_type(4))) float f32x4;
typedef __attribute__((ext_vector_type(16))) float f32x16;
typedef __attribute__((ext_vector_type(4))) int   i32x4;

__device__ __forceinline__ unsigned f2bf_u(float f) {
    unsigned u = __builtin_bit_cast(unsigned, f);
    return (u + 0x7fffu + ((u >> 16) & 1u)) >> 16;   // RNE bf16
}
__device__ __forceinline__ unsigned pack2bf(float lo, float hi) {
    return f2bf_u(lo) | (f2bf_u(hi) << 16);
}
union U4BF8 { uint4 u; bf16x8 v; };

__device__ __forceinline__ void async_copy16(const ushort* g, ushort* l) {
    __builtin_amdgcn_global_load_lds(
        (const __attribute__((address_space(1))) unsigned*)g,
        (__attribute__((address_space(3))) unsigned*)l, 16, 0, 0);
}

// Kernel 0: W fp32 [512][256] -> WB bf16 in MFMA-B layout ((k>>3)*256+c)*8+(k&7).
__global__ __launch_bounds__(256) void wb_kernel(const float* __restrict__ W,
                                                 ushort* __restrict__ WB) {
    const int g = blockIdx.x * 256 + threadIdx.x;   // 64*256 = 16384
    const int c = g & 255, k8 = g >> 8;
    const float* wp = W + (size_t)(k8 * 8) * DOUT + c;
    U4BF8 o;
    o.u.x = pack2bf(wp[0 * DOUT], wp[1 * DOUT]);
    o.u.y = pack2bf(wp[2 * DOUT], wp[3 * DOUT]);
    o.u.z = pack2bf(wp[4 * DOUT], wp[5 * DOUT]);
    o.u.w = pack2bf(wp[6 * DOUT], wp[7 * DOUT]);
    *(uint4*)(WB + (size_t)g * 8) = o.u;
}

// Kernel 1: h = X@W + b via MFMA, split-K across 4 waves (unchanged from R0).
__global__ __launch_bounds__(256) void h_kernel(
        const float* __restrict__ X, const ushort* __restrict__ WB,
        const float* __restrict__ bvec, const float* __restrict__ a,
        ushort* __restrict__ hB, float* __restrict__ el, float* __restrict__ er)
{
    __shared__ float red[4][64][65];
    __shared__ float elr[2][4][16];
    const int t = threadIdx.x;
    const int w = t >> 6, l = t & 63, q = l >> 4, n = l & 15;
    const int i0 = blockIdx.x * 16;
    f32x4 acc[16];
    #pragma unroll
    for (int ct = 0; ct < 16; ++ct) acc[ct] = (f32x4){0.f, 0.f, 0.f, 0.f};
    const float* xp = X + (size_t)(i0 + n) * DIN + q * 8;

    #pragma unroll
    for (int ks = 0; ks < 4; ++ks) {
        const int k0 = w * 128 + ks * 32;
        const float4 x0 = *(const float4*)(xp + k0);
        const float4 x1 = *(const float4*)(xp + k0 + 4);
        U4BF8 pa;
        pa.u.x = pack2bf(x0.x, x0.y); pa.u.y = pack2bf(x0.z, x0.w);
        pa.u.z = pack2bf(x1.x, x1.y); pa.u.w = pack2bf(x1.z, x1.w);
        const ushort* wbp = WB + ((k0 >> 3) + q) * 2048 + n * 8;
        bf16x8 bfr[16];
        #pragma unroll
        for (int ct = 0; ct < 16; ++ct) bfr[ct] = *(const bf16x8*)(wbp + ct * 128);
        #pragma unroll
        for (int ct = 0; ct < 16; ++ct)
            acc[ct] = __builtin_amdgcn_mfma_f32_16x16x32_bf16(pa.v, bfr[ct], acc[ct], 0, 0, 0);
    }
    #pragma unroll
    for (int ct = 0; ct < 16; ++ct)
        #pragma unroll
        for (int r = 0; r < 4; ++r) red[w][l][ct * 4 + r] = acc[ct][r];
    __syncthreads();

    float pl[4] = {0.f, 0.f, 0.f, 0.f}, pr[4] = {0.f, 0.f, 0.f, 0.f};
    const int hbase = (blockIdx.x * 2 + (q >> 1)) * 2048 + n * 8 + (q & 1) * 4;
    #pragma unroll
    for (int c2 = 0; c2 < 4; ++c2) {
        const int ct = w * 4 + c2;
        const float bb = bvec[ct * 16 + n];
        const float al = a[ct * 16 + n];
        const float ar = a[DOUT + ct * 16 + n];
        float v[4];
        #pragma unroll
        for (int r = 0; r < 4; ++r) {
            v[r] = red[0][l][ct * 4 + r] + red[1][l][ct * 4 + r]
                 + red[2][l][ct * 4 + r] + red[3][l][ct * 4 + r] + bb;
            pl[r] += v[r] * al;
            pr[r] += v[r] * ar;
        }
        ushort4 hp;
        hp.x = (ushort)f2bf_u(v[0]); hp.y = (ushort)f2bf_u(v[1]);
        hp.z = (ushort)f2bf_u(v[2]); hp.w = (ushort)f2bf_u(v[3]);
        *(ushort4*)&hB[hbase + ct * 128] = hp;
    }
    #pragma unroll
    for (int r = 0; r < 4; ++r) {
        #pragma unroll
        for (int off = 1; off < 16; off <<= 1) {
            pl[r] += __shfl_xor(pl[r], off);
            pr[r] += __shfl_xor(pr[r], off);
        }
    }
    if (n == 0) {
        #pragma unroll
        for (int r = 0; r < 4; ++r) {
            elr[0][w][q * 4 + r] = pl[r];
            elr[1][w][q * 4 + r] = pr[r];
        }
    }
    __syncthreads();
    if (t < 16) {
        el[i0 + t] = elr[0][0][t] + elr[0][1][t] + elr[0][2][t] + elr[0][3][t];
        er[i0 + t] = elr[1][0][t] + elr[1][1][t] + elr[1][2][t] + elr[1][3][t];
    }
}

// 8 masked-exp lanes -> one packed A-fragment word-group + running sum.
#define EXP8(ELM, E0, E1, M0, M1, PA, LS)                                          \
    {                                                                              \
        float v, p0, p1, p2, p3, p4, p5, p6, p7;                                   \
        v = ELM + E0.x; v = fmaxf(v, ALPHA * v); p0 = __expf(M0.x > 0 ? v : NEG_INF); \
        v = ELM + E0.y; v = fmaxf(v, ALPHA * v); p1 = __expf(M0.y > 0 ? v : NEG_INF); \
        v = ELM + E0.z; v = fmaxf(v, ALPHA * v); p2 = __expf(M0.z > 0 ? v : NEG_INF); \
        v = ELM + E0.w; v = fmaxf(v, ALPHA * v); p3 = __expf(M0.w > 0 ? v : NEG_INF); \
        v = ELM + E1.x; v = fmaxf(v, ALPHA * v); p4 = __expf(M1.x > 0 ? v : NEG_INF); \
        v = ELM + E1.y; v = fmaxf(v, ALPHA * v); p5 = __expf(M1.y > 0 ? v : NEG_INF); \
        v = ELM + E1.z; v = fmaxf(v, ALPHA * v); p6 = __expf(M1.z > 0 ? v : NEG_INF); \
        v = ELM + E1.w; v = fmaxf(v, ALPHA * v); p7 = __expf(M1.w > 0 ? v : NEG_INF); \
        LS += p0 + p1 + p2 + p3 + p4 + p5 + p6 + p7;                               \
        PA.u.x = pack2bf(p0, p1); PA.u.y = pack2bf(p2, p3);                        \
        PA.u.z = pack2bf(p4, p5); PA.u.w = pack2bf(p6, p7);                        \
    }

// Kernel 2 (v8): v7 grid/step structure (512 blocks = 64 rb x 8 je -> 2
// blocks/CU; 16 steps of 64 j; 2x32KB stage + 4KB ers = 68 KB) combined with
// v6's verified ct-split 32x32x16 compute: wave = rg (32 rows) x ch (128 c).
// Per-wave B-frag reads per step: 16 b128 (its col-half) -> per-CU LDS read
// traffic halved vs v7; MFMA inst count halved; acc = 64 VGPR. adj double-
// buffered at 2-ks granularity (adjA/adjB, 16 VGPR each) to stay <=128 VGPR.
__global__ __launch_bounds__(512, 4) void attn_kernel(
        const int* __restrict__ adj, const float* __restrict__ el,
        const float* __restrict__ er, const float* __restrict__ ab,
        const ushort* __restrict__ hB, float* __restrict__ pout,
        float* __restrict__ plsum)
{
    __shared__ ushort stage[2][16384];   // 2 x 32 KB (64 j x 256 c bf16)
    __shared__ float ers[1024];          // 4 KB
    const int t = threadIdx.x;
    const int w = t >> 6, l = t & 63;
    const int rg = w >> 1, ch = w & 1;   // row-group (32 rows), col-half (128 c)
    const int r32 = l & 31, hi = l >> 5;
    const int rb = blockIdx.x >> 3, je = blockIdx.x & 7;
    const int j0 = je * 1024;
    const int row = rb * 128 + rg * 32 + r32;
    const float elm = el[row] + ab[0];
    const int* alp = adj + (size_t)row * N + j0 + hi * 8;

    f32x16 acc[4];
    #pragma unroll
    for (int ct = 0; ct < 4; ++ct)
        #pragma unroll
        for (int r = 0; r < 16; ++r) acc[ct][r] = 0.f;
    float lsum = 0.f;

    // prologue: er eighth -> LDS; adj regs for step 0; hB step-0 tile -> stage[0]
    if (t < 256) *(float4*)&ers[t * 4] = *(const float4*)&er[j0 + t * 4];
    i32x4 adjA[4], adjB[4];
    adjA[0] = *(const i32x4*)(alp +  0); adjA[1] = *(const i32x4*)(alp +  4);  // ks0
    adjA[2] = *(const i32x4*)(alp + 16); adjA[3] = *(const i32x4*)(alp + 20);  // ks1
    adjB[0] = *(const i32x4*)(alp + 32); adjB[1] = *(const i32x4*)(alp + 36);  // ks2
    adjB[2] = *(const i32x4*)(alp + 48); adjB[3] = *(const i32x4*)(alp + 52);  // ks3
    {
        const ushort* g = hB + (size_t)j0 * 256 + t * 8;
        ushort* lb = &stage[0][t * 8];
        #pragma unroll
        for (int i = 0; i < 4; ++i) async_copy16(g + i * 4096, lb + i * 4096);
    }

    for (int s = 0; s < 16; ++s) {
        __syncthreads();                 // stage[s&1] + ers + adj regs ready
        if (s < 15) {                    // next hB tile (flies during this step)
            const ushort* g = hB + (size_t)(j0 + (s + 1) * 64) * 256 + t * 8;
            ushort* lb = &stage[(s + 1) & 1][t * 8];
            #pragma unroll
            for (int i = 0; i < 4; ++i) async_copy16(g + i * 4096, lb + i * 4096);
        }
        const ushort* sbase = &stage[s & 1][ch * 1024 + r32 * 8];

        // phase A: k-slices 0,1 (j = s*64 + ks*16 + hi*8 + 0..7)
        U4BF8 pa0, pa1;
        {
            const float4 e00 = *(const float4*)&ers[s * 64 +  0 + hi * 8];
            const float4 e01 = *(const float4*)&ers[s * 64 +  0 + hi * 8 + 4];
            EXP8(elm, e00, e01, adjA[0], adjA[1], pa0, lsum);
            const float4 e10 = *(const float4*)&ers[s * 64 + 16 + hi * 8];
            const float4 e11 = *(const float4*)&ers[s * 64 + 16 + hi * 8 + 4];
            EXP8(elm, e10, e11, adjA[2], adjA[3], pa1, lsum);
        }
        if (s < 15) {                    // refill adjA for step s+1
            const int* ap = alp + (s + 1) * 64;
            adjA[0] = *(const i32x4*)(ap +  0); adjA[1] = *(const i32x4*)(ap +  4);
            adjA[2] = *(const i32x4*)(ap + 16); adjA[3] = *(const i32x4*)(ap + 20);
        }
        {
            const ushort* sb0 = sbase + (0 + hi) * 2048;   // jg = ks0*2 + hi
            const ushort* sb1 = sbase + (2 + hi) * 2048;   // jg = ks1*2 + hi
            #pragma unroll
            for (int ct = 0; ct < 4; ++ct) {
                const bf16x8 bf = *(const bf16x8*)(sb0 + ct * 256);
                acc[ct] = __builtin_amdgcn_mfma_f32_32x32x16_bf16(pa0.v, bf, acc[ct], 0, 0, 0);
            }
            #pragma unroll
            for (int ct = 0; ct < 4; ++ct) {
                const bf16x8 bf = *(const bf16x8*)(sb1 + ct * 256);
                acc[ct] = __builtin_amdgcn_mfma_f32_32x32x16_bf16(pa1.v, bf, acc[ct], 0, 0, 0);
            }
        }

        // phase B: k-slices 2,3
        U4BF8 pa2, pa3;
        {
            const float4 e20 = *(const float4*)&ers[s * 64 + 32 + hi * 8];
            const float4 e21 = *(const float4*)&ers[s * 64 + 32 + hi * 8 + 4];
            EXP8(elm, e20, e21, adjB[0], adjB[1], pa2, lsum);
            const float4 e30 = *(const float4*)&ers[s * 64 + 48 + hi * 8];
            const float4 e31 = *(const float4*)&ers[s * 64 + 48 + hi * 8 + 4];
            EXP8(elm, e30, e31, adjB[2], adjB[3], pa3, lsum);
        }
        if (s < 15) {                    // refill adjB for step s+1
            const int* ap = alp + (s + 1) * 64;
            adjB[0] = *(const i32x4*)(ap + 32); adjB[1] = *(const i32x4*)(ap + 36);
            adjB[2] = *(const i32x4*)(ap + 48); adjB[3] = *(const i32x4*)(ap + 52);
        }
        {
            const ushort* sb2 = sbase + (4 + hi) * 2048;   // jg = ks2*2 + hi
            const ushort* sb3 = sbase + (6 + hi) * 2048;   // jg = ks3*2 + hi
            #pragma unroll
            for (int ct = 0; ct < 4; ++ct) {
                const bf16x8 bf = *(const bf16x8*)(sb2 + ct * 256);
                acc[ct] = __builtin_amdgcn_mfma_f32_32x32x16_bf16(pa2.v, bf, acc[ct], 0, 0, 0);
            }
            #pragma unroll
            for (int ct = 0; ct < 4; ++ct) {
                const bf16x8 bf = *(const bf16x8*)(sb3 + ct * 256);
                acc[ct] = __builtin_amdgcn_mfma_f32_32x32x16_bf16(pa3.v, bf, acc[ct], 0, 0, 0);
            }
        }
    }

    // row sums: lanes l and l^32 hold complementary j-sets of the same row;
    // ch pair computes identical sums, only ch==0 writes.
    lsum += __shfl_xor(lsum, 32);
    if (ch == 0 && l < 32)
        plsum[(size_t)je * N + rb * 128 + rg * 32 + l] = lsum;

    // unnormalized partial tile. C/D 32x32: col = ch*128 + ct*32 + r32,
    // row = (r&3) + 8*(r>>2) + 4*hi  (v6-verified mapping).
    float* pb = pout + ((size_t)je * N + rb * 128 + rg * 32) * 256 + ch * 128 + r32;
    #pragma unroll
    for (int ct = 0; ct < 4; ++ct)
        #pragma unroll
        for (int r = 0; r < 16; ++r) {
            const int rl = (r & 3) + 8 * (r >> 2) + 4 * hi;
            __builtin_nontemporal_store(acc[ct][r], pb + (size_t)rl * 256 + ct * 32);
        }
}

// Kernel 3: combine 8 j-eighth partials + normalize. grid 2048 x 256.
__global__ __launch_bounds__(256) void combine_kernel(
        const float* __restrict__ pout, const float* __restrict__ plsum,
        float* __restrict__ out)
{
    const int t = threadIdx.x;
    const int row = blockIdx.x * 4 + (t >> 6);
    const int c = (t & 63) * 4;
    const size_t idx = (size_t)row * 256 + c;
    const size_t qs = (size_t)N * 256;
    float4 acc = *(const float4*)&pout[idx];
    float ls = plsum[row];
    #pragma unroll
    for (int k = 1; k < 8; ++k) {
        const float4 v = *(const float4*)&pout[idx + k * qs];
        acc.x += v.x; acc.y += v.y; acc.z += v.z; acc.w += v.w;
        ls += plsum[k * N + row];
    }
    const float li = 1.0f / ls;
    float4 o;
    o.x = acc.x * li; o.y = acc.y * li; o.z = acc.z * li; o.w = acc.w * li;
    *(float4*)&out[idx] = o;
}

extern "C" void kernel_launch(void* const* d_in, const int* in_sizes, int n_in,
                              void* d_out, int out_size, void* d_ws, size_t ws_size,
                              hipStream_t stream) {
    const int*   adj = (const int*)  d_in[0];
    const float* X   = (const float*)d_in[1];
    const float* W   = (const float*)d_in[2];
    const float* b   = (const float*)d_in[3];
    const float* a   = (const float*)d_in[4];
    const float* ab  = (const float*)d_in[5];
    float* out = (float*)d_out;

    ushort* hB    = (ushort*)d_ws;                        // 4 MB
    ushort* WB    = hB + (size_t)N * DOUT;                // 256 KB
    float*  el    = (float*)(WB + (size_t)DIN * DOUT);    // 32 KB
    float*  er    = el + N;                               // 32 KB
    float*  plsum = er + N;                               // 8*N fp32 = 256 KB
    float*  pout  = plsum + 8 * N;                        // 8*N*256 fp32 = 64 MB

    wb_kernel<<<dim3(64), dim3(256), 0, stream>>>(W, WB);
    h_kernel<<<dim3(N / 16), dim3(256), 0, stream>>>(X, WB, b, a, hB, el, er);
    attn_kernel<<<dim3(512), dim3(512), 0, stream>>>(adj, el, er, ab, hB, pout, plsum);
    combine_kernel<<<dim3(N / 4), dim3(256), 0, stream>>>(pout, plsum, out);
}